// Round 2
// baseline (187.985 us; speedup 1.0000x reference)
//
#include <hip/hip_runtime.h>

#define LSEQ 256
#define DMODEL 512
#define NHEAD 8
#define DKH 64
#define BATCH 4

// ---------------------------------------------------------------------------
// fp32 GEMM body: C(M,N) = X(M,K) @ W(K,N) + bias, with mode-based output layout
// mode 0: row-major (B*L, D)
// mode 1: qh/vh layout  [((b*H+h)*L + l)*DK + dk]
// mode 2: kT layout     [((b*H+h)*DK + dk)*L + l]
// ---------------------------------------------------------------------------
__device__ __forceinline__ void gemm_body(
    const float* __restrict__ X, const float* __restrict__ W,
    const float* __restrict__ bias, float* __restrict__ out, int mode)
{
  constexpr int M = BATCH * LSEQ, N = DMODEL, K = DMODEL;
  constexpr int BM = 64, BN = 64, BK = 16;
  __shared__ float As[BK][BM + 4];   // As[k][m], row = 272B (16B aligned)
  __shared__ float Bs[BK][BN + 4];
  const int tid = threadIdx.x;
  const int bm = blockIdx.x * BM, bn = blockIdx.y * BN;
  const int tx = tid & 15, ty = tid >> 4;
  const int arow = tid >> 2, akk = (tid & 3) << 2;
  const int bkk = tid >> 4, bcol = (tid & 15) << 2;
  float acc[4][4] = {};
  for (int k0 = 0; k0 < K; k0 += BK) {
    float4 av = *(const float4*)&X[(bm + arow) * K + k0 + akk];
    float4 bv = *(const float4*)&W[(k0 + bkk) * N + bn + bcol];
    As[akk + 0][arow] = av.x;
    As[akk + 1][arow] = av.y;
    As[akk + 2][arow] = av.z;
    As[akk + 3][arow] = av.w;
    *(float4*)&Bs[bkk][bcol] = bv;
    __syncthreads();
#pragma unroll
    for (int kk = 0; kk < BK; ++kk) {
      float a_[4], b_[4];
      *(float4*)a_ = *(const float4*)&As[kk][ty << 2];
      *(float4*)b_ = *(const float4*)&Bs[kk][tx << 2];
#pragma unroll
      for (int im = 0; im < 4; ++im)
#pragma unroll
        for (int jn = 0; jn < 4; ++jn)
          acc[im][jn] = fmaf(a_[im], b_[jn], acc[im][jn]);
    }
    __syncthreads();
  }
  // epilogue
#pragma unroll
  for (int im = 0; im < 4; ++im) {
    const int r = bm + (ty << 2) + im;
    const int b = r >> 8, l = r & (LSEQ - 1);
    if (mode == 0) {
      float4 v;
      float* vp_ = (float*)&v;
#pragma unroll
      for (int jn = 0; jn < 4; ++jn) {
        const int n = bn + (tx << 2) + jn;
        vp_[jn] = acc[im][jn] + bias[n];
      }
      *(float4*)&out[r * N + bn + (tx << 2)] = v;
    } else if (mode == 1) {
      const int n0 = bn + (tx << 2);
      const int h = n0 >> 6, dk0 = n0 & 63;
      float4 v;
      float* vp_ = (float*)&v;
#pragma unroll
      for (int jn = 0; jn < 4; ++jn) vp_[jn] = acc[im][jn] + bias[n0 + jn];
      *(float4*)&out[((b * NHEAD + h) * LSEQ + l) * DKH + dk0] = v;
    } else {
#pragma unroll
      for (int jn = 0; jn < 4; ++jn) {
        const int n = bn + (tx << 2) + jn;
        const int h = n >> 6, dk = n & 63;
        out[((b * NHEAD + h) * DKH + dk) * LSEQ + l] = acc[im][jn] + bias[n];
      }
    }
  }
}

__global__ __launch_bounds__(256) void proj_qkv_kernel(
    const float* __restrict__ q, const float* __restrict__ k, const float* __restrict__ v,
    const float* __restrict__ Wq, const float* __restrict__ bq,
    const float* __restrict__ Wk, const float* __restrict__ bk,
    const float* __restrict__ Wv, const float* __restrict__ bv,
    float* __restrict__ qh, float* __restrict__ kT, float* __restrict__ vh)
{
  if (blockIdx.z == 0) gemm_body(q, Wq, bq, qh, 1);
  else if (blockIdx.z == 1) gemm_body(k, Wk, bk, kT, 2);
  else gemm_body(v, Wv, bv, vh, 1);
}

__global__ __launch_bounds__(256) void out_proj_kernel(
    const float* __restrict__ X, const float* __restrict__ W0,
    const float* __restrict__ b0, float* __restrict__ out)
{
  gemm_body(X, W0, b0, out, 0);
}

// ---------------------------------------------------------------------------
// Fused Bahdanau attention: per (b,h, 32 q-rows) block, 8 waves.
//   ksh[d][j]   : K^T tile (conflict-free b32 reads, lanes = consecutive j)
//   vsh[j][dk]  : V tile (b128 reads per lane-group)
//   scores[i][j] = sum_d vp[d] * tanh(q[i][d] + k[j][d]); softmax; out = P @ V
// ---------------------------------------------------------------------------
__global__ __launch_bounds__(512) void attn_kernel(
    const float* __restrict__ qh,   // (B,H,L,DK)
    const float* __restrict__ kT,   // (B,H,DK,L)
    const float* __restrict__ vh,   // (B,H,L,DK)
    const int* __restrict__ mask,   // (B,L,L)
    const float* __restrict__ vp,   // (H,DK)
    float* __restrict__ out)        // (B,L,D)
{
  __shared__ float ksh[DKH][LSEQ];      // 64 KB
  __shared__ float vsh[LSEQ][DKH];      // 64 KB
  __shared__ float qsh[32][DKH];        // 8 KB
  __shared__ float psh[8][LSEQ];        // 8 KB (one P-row per wave)
  __shared__ float vpsh[DKH];

  const int bh = blockIdx.x;            // 0..31
  const int b = bh >> 3, h = bh & 7;
  const int i0 = blockIdx.y * 32;
  const int tid = threadIdx.x;
  const int lane = tid & 63, w = tid >> 6;

  // ---- stage K^T, V, Q, vp ----
  const float* kbase = kT + bh * (DKH * LSEQ);
  for (int t = tid; t < DKH * LSEQ / 4; t += 512) {
    const int d = t >> 6, j4 = (t & 63) << 2;
    *(float4*)&ksh[d][j4] = *(const float4*)&kbase[d * LSEQ + j4];
  }
  const float* vbase = vh + bh * (LSEQ * DKH);
  for (int t = tid; t < LSEQ * DKH / 4; t += 512) {
    const int j = t >> 4, d4 = (t & 15) << 2;
    *(float4*)&vsh[j][d4] = *(const float4*)&vbase[j * DKH + d4];
  }
  const float* qbase = qh + (bh * LSEQ + i0) * DKH;
  for (int t = tid; t < 32 * DKH / 4; t += 512) {
    const int r = t >> 4, d4 = (t & 15) << 2;
    *(float4*)&qsh[r][d4] = *(const float4*)&qbase[r * DKH + d4];
  }
  if (tid < DKH) vpsh[tid] = vp[h * DKH + tid];
  __syncthreads();

  const float LOG2E = 1.44269504089f;
  const float TWO_LOG2E = 2.88539008178f;

  for (int ii = 0; ii < 4; ++ii) {
    const int il = (w << 2) + ii;       // local q-row 0..31
    const int i = i0 + il;

    // ---- scores: s[c] = score(i, c*64+lane) ----
    float s[4] = {0.f, 0.f, 0.f, 0.f};
#pragma unroll 4
    for (int g = 0; g < 16; ++g) {      // 4 d's per iteration
      float q_[4], vpv[4];
      *(float4*)q_ = *(const float4*)&qsh[il][g << 2];
      *(float4*)vpv = *(const float4*)&vpsh[g << 2];
#pragma unroll
      for (int c = 0; c < 4; ++c) {
        const int j = (c << 6) + lane;
#pragma unroll
        for (int t = 0; t < 4; ++t) {
          const float x = q_[t] + ksh[(g << 2) + t][j];
          const float e = __builtin_amdgcn_exp2f(TWO_LOG2E * x);
          const float th = fmaf(-2.f, __builtin_amdgcn_rcpf(e + 1.f), 1.f);
          s[c] = fmaf(vpv[t], th, s[c]);
        }
      }
    }

    // ---- mask ----
    const int* mrow = mask + (b * LSEQ + i) * LSEQ;
#pragma unroll
    for (int c = 0; c < 4; ++c) {
      const int mv = mrow[(c << 6) + lane];
      s[c] = mv ? s[c] : -1.0e9f;
    }

    // ---- softmax across 256 (4 regs x 64 lanes) ----
    float m = fmaxf(fmaxf(s[0], s[1]), fmaxf(s[2], s[3]));
#pragma unroll
    for (int off = 32; off; off >>= 1) m = fmaxf(m, __shfl_xor(m, off));
    float p[4];
    float sum = 0.f;
#pragma unroll
    for (int c = 0; c < 4; ++c) {
      p[c] = __builtin_amdgcn_exp2f((s[c] - m) * LOG2E);
      sum += p[c];
    }
#pragma unroll
    for (int off = 32; off; off >>= 1) sum += __shfl_xor(sum, off);
    const float rs = __builtin_amdgcn_rcpf(sum);
#pragma unroll
    for (int c = 0; c < 4; ++c) psh[w][(c << 6) + lane] = p[c] * rs;

    // ---- PV: lane group cg = j-quarter, qq = dk-quad ----
    const int cg = lane >> 4, qq = lane & 15;
    float o[4] = {0.f, 0.f, 0.f, 0.f};
#pragma unroll 4
    for (int jg = 0; jg < 16; ++jg) {
      float pv[4];
      *(float4*)pv = *(const float4*)&psh[w][(cg << 6) + (jg << 2)];
#pragma unroll
      for (int t = 0; t < 4; ++t) {
        float v_[4];
        *(float4*)v_ = *(const float4*)&vsh[(cg << 6) + (jg << 2) + t][qq << 2];
#pragma unroll
        for (int u = 0; u < 4; ++u) o[u] = fmaf(pv[t], v_[u], o[u]);
      }
    }
    // reduce across the 4 j-quarter groups (lanes qq, qq+16, qq+32, qq+48)
#pragma unroll
    for (int off = 16; off <= 32; off <<= 1) {
#pragma unroll
      for (int u = 0; u < 4; ++u) o[u] += __shfl_xor(o[u], off);
    }
    if (lane < 16) {
      float* op = out + (b * LSEQ + i) * DMODEL + h * DKH + (qq << 2);
      *(float4*)op = *(float4*)o;
    }
  }
}

// ---------------------------------------------------------------------------
extern "C" void kernel_launch(void* const* d_in, const int* in_sizes, int n_in,
                              void* d_out, int out_size, void* d_ws, size_t ws_size,
                              hipStream_t stream) {
  const float* q   = (const float*)d_in[0];
  const float* k   = (const float*)d_in[1];
  const float* v   = (const float*)d_in[2];
  const int*  mask = (const int*)d_in[3];
  const float* Wq  = (const float*)d_in[4];
  const float* bq  = (const float*)d_in[5];
  const float* Wk  = (const float*)d_in[6];
  const float* bk  = (const float*)d_in[7];
  const float* Wv  = (const float*)d_in[8];
  const float* bv  = (const float*)d_in[9];
  const float* vp  = (const float*)d_in[10];
  const float* W0  = (const float*)d_in[11];
  const float* b0  = (const float*)d_in[12];
  float* outp = (float*)d_out;

  float* ws = (float*)d_ws;
  const int SZ = BATCH * LSEQ * DMODEL;   // 524288
  float* qh  = ws;
  float* kT  = ws + SZ;
  float* vhW = ws + 2 * SZ;
  float* ao  = ws + 3 * SZ;

  proj_qkv_kernel<<<dim3(16, 8, 3), 256, 0, stream>>>(q, k, v, Wq, bq, Wk, bk, Wv, bv,
                                                      qh, kT, vhW);
  attn_kernel<<<dim3(32, 8), 512, 0, stream>>>(qh, kT, vhW, mask, vp, ao);
  out_proj_kernel<<<dim3(16, 8), 256, 0, stream>>>(ao, W0, b0, outp);
}